// Round 5
// baseline (374.289 us; speedup 1.0000x reference)
//
#include <hip/hip_runtime.h>
#include <math.h>

#define B_TOT   262144ll
#define LOG_OFF 26214400ll   // delta = B*5*20
#define A_OFF   27262976ll   // + B*4

// workspace float offsets
#define WS_A4   0     // 4*25 softmaxed adjacencies
#define WS_ENCB 112   // 4*32 encoder bias per emotion (includes enc_b + e@enc_w[20:])

// LDS float offsets (all float4 regions 16B-aligned)
#define L_ENCW 0      // 20*32
#define L_W1   640    // 32*32
#define L_W2   1664   // 32*20
#define L_CLS  2304   // 160*4
#define L_ENCB 2944   // 4*32
#define L_A4   3072   // 100 (pad to 104)
#define L_B1   3176   // 32
#define L_LNG  3208   // 32
#define L_LNB  3240   // 32
#define L_B2   3272   // 20
#define L_CLSB 3292   // 4 (pad to 3312)
#define L_HST  3312   // 4 waves * 60 rows * pitch 36
#define L_AUX  11952  // 48 batches * 5 * 4
#define L_TOT  12912  // 51.6 KB -> 3 blocks/CU

__device__ __forceinline__ void fma4(float a, float4 w, float* acc) {
    acc[0] = fmaf(a, w.x, acc[0]);
    acc[1] = fmaf(a, w.y, acc[1]);
    acc[2] = fmaf(a, w.z, acc[2]);
    acc[3] = fmaf(a, w.w, acc[3]);
}

// ---------- precompute: 4 adjacency matrices + 4 encoder bias vectors ----------
__global__ void __launch_bounds__(128) precomp_kernel(
    const float* __restrict__ emo_emb, const float* __restrict__ A_w1,
    const float* __restrict__ A_b1, const float* __restrict__ A_w2,
    const float* __restrict__ A_b2, const float* __restrict__ enc_w,
    const float* __restrict__ enc_b, float* __restrict__ wsf)
{
    __shared__ float hid[4][32];
    __shared__ float av[4][25];
    const int t = threadIdx.x;
    const int c = t >> 5, m = t & 31;

    // hidden = relu(e @ A_w1 + A_b1)
    float acc = A_b1[m];
    #pragma unroll
    for (int k = 0; k < 16; ++k)
        acc = fmaf(emo_emb[c*16 + k], A_w1[k*32 + m], acc);
    hid[c][m] = fmaxf(acc, 0.f);
    __syncthreads();

    // a = hidden @ A_w2 + A_b2
    if (m < 25) {
        float a2 = A_b2[m];
        #pragma unroll
        for (int k = 0; k < 32; ++k)
            a2 = fmaf(hid[c][k], A_w2[k*25 + m], a2);
        av[c][m] = a2;
    }
    __syncthreads();

    // row softmax -> ws A4
    if (m < 5) {
        float v[5];
        #pragma unroll
        for (int q = 0; q < 5; ++q) v[q] = av[c][m*5 + q];
        float mx = v[0];
        #pragma unroll
        for (int q = 1; q < 5; ++q) mx = fmaxf(mx, v[q]);
        float ssum = 0.f;
        #pragma unroll
        for (int q = 0; q < 5; ++q) { v[q] = expf(v[q] - mx); ssum += v[q]; }
        float inv = 1.f / ssum;
        #pragma unroll
        for (int q = 0; q < 5; ++q) wsf[WS_A4 + c*25 + m*5 + q] = v[q] * inv;
    }

    // encoder bias per emotion: enc_b + e @ enc_w[20:]
    float eb = enc_b[m];
    #pragma unroll
    for (int k = 0; k < 16; ++k)
        eb = fmaf(emo_emb[c*16 + k], enc_w[(20 + k)*32 + m], eb);
    wsf[WS_ENCB + c*32 + m] = eb;
}

// ---------- main: lane = (batch, node); 12 batches per wave ----------
__global__ void __launch_bounds__(256) main_kernel(
    const float* __restrict__ nf, const int* __restrict__ emo_idx,
    const float* __restrict__ enc_w, const float* __restrict__ ln_g,
    const float* __restrict__ ln_b, const float* __restrict__ w1,
    const float* __restrict__ b1, const float* __restrict__ w2,
    const float* __restrict__ b2, const float* __restrict__ clsw,
    const float* __restrict__ clsb, const float* __restrict__ wsf,
    float* __restrict__ out)
{
    __shared__ __align__(16) float s[L_TOT];
    const int tid = threadIdx.x;

    for (int t = tid; t < 640;  t += 256) s[L_ENCW + t] = enc_w[t];   // rows 0..19 only
    for (int t = tid; t < 1024; t += 256) s[L_W1 + t]   = w1[t];
    for (int t = tid; t < 640;  t += 256) s[L_W2 + t]   = w2[t];
    for (int t = tid; t < 640;  t += 256) s[L_CLS + t]  = clsw[t];
    if (tid < 128) s[L_ENCB + tid] = wsf[WS_ENCB + tid];
    if (tid < 100) s[L_A4 + tid]   = wsf[WS_A4 + tid];
    if (tid < 32) { s[L_B1 + tid] = b1[tid]; s[L_LNG + tid] = ln_g[tid]; s[L_LNB + tid] = ln_b[tid]; }
    if (tid < 20) s[L_B2 + tid] = b2[tid];
    if (tid < 4)  s[L_CLSB + tid] = clsb[tid];
    __syncthreads();

    const int wave = tid >> 6, lane = tid & 63;
    const int g = lane / 5, n = lane - g*5;            // batch-in-wave, node
    const long long b = (long long)blockIdx.x * 48 + wave*12 + g;
    const bool act = (lane < 60) && (b < B_TOT);

    int emo = 0;
    float x[20];
    #pragma unroll
    for (int d = 0; d < 20; ++d) x[d] = 0.f;
    if (act) {
        emo = emo_idx[b];
        const float4* xp = (const float4*)(nf + b*100ll + n*20);
        #pragma unroll
        for (int t = 0; t < 5; ++t) {
            float4 v = xp[t];
            x[4*t+0] = v.x; x[4*t+1] = v.y; x[4*t+2] = v.z; x[4*t+3] = v.w;
        }
    }

    // ---- encoder: y = x @ enc_w[:20] + encb[emo] ----
    float y[32];
    {
        const float4* ev = (const float4*)&s[L_ENCB];
        #pragma unroll
        for (int j4 = 0; j4 < 8; ++j4) {
            float4 v = ev[emo*8 + j4];
            y[4*j4+0] = v.x; y[4*j4+1] = v.y; y[4*j4+2] = v.z; y[4*j4+3] = v.w;
        }
        const float4* wv = (const float4*)&s[L_ENCW];
        #pragma unroll
        for (int d = 0; d < 20; ++d) {
            float xv = x[d];
            #pragma unroll
            for (int j4 = 0; j4 < 8; ++j4)
                fma4(xv, wv[d*8 + j4], y + 4*j4);
        }
    }

    // ---- LayerNorm + relu (in-lane over 32 regs) ----
    {
        float sum = 0.f;
        #pragma unroll
        for (int j = 0; j < 32; ++j) sum += y[j];
        float mu = sum * 0.03125f;
        float sq = 0.f;
        #pragma unroll
        for (int j = 0; j < 32; ++j) { float d = y[j] - mu; sq = fmaf(d, d, sq); }
        float rs = rsqrtf(fmaf(sq, 0.03125f, 1e-5f));
        const float4* gv = (const float4*)&s[L_LNG];
        const float4* bv = (const float4*)&s[L_LNB];
        #pragma unroll
        for (int j4 = 0; j4 < 8; ++j4) {
            float4 gg = gv[j4], bb = bv[j4];
            float h0 = fmaf((y[4*j4+0] - mu) * rs, gg.x, bb.x);
            float h1 = fmaf((y[4*j4+1] - mu) * rs, gg.y, bb.y);
            float h2 = fmaf((y[4*j4+2] - mu) * rs, gg.z, bb.z);
            float h3 = fmaf((y[4*j4+3] - mu) * rs, gg.w, bb.w);
            y[4*j4+0] = fmaxf(h0, 0.f); y[4*j4+1] = fmaxf(h1, 0.f);
            y[4*j4+2] = fmaxf(h2, 0.f); y[4*j4+3] = fmaxf(h3, 0.f);
        }
    }

    // ---- stage h in LDS (per-wave region; cross-lane dep within wave only) ----
    if (act) {
        float4* hp = (float4*)&s[L_HST + (wave*60 + lane)*36];
        #pragma unroll
        for (int t = 0; t < 8; ++t)
            hp[t] = make_float4(y[4*t], y[4*t+1], y[4*t+2], y[4*t+3]);
    }
    asm volatile("s_waitcnt lgkmcnt(0)" ::: "memory");

    // ---- agg: h_agg[i=n] = sum_nn A4[emo][n][nn] * h[g,nn] ----
    float hagg[32];
    #pragma unroll
    for (int j = 0; j < 32; ++j) hagg[j] = 0.f;
    if (act) {
        #pragma unroll
        for (int nn = 0; nn < 5; ++nn) {
            float a = s[L_A4 + emo*25 + n*5 + nn];
            const float4* rp = (const float4*)&s[L_HST + (wave*60 + g*5 + nn)*36];
            #pragma unroll
            for (int t = 0; t < 8; ++t)
                fma4(a, rp[t], hagg + 4*t);
        }
    }

    // ---- out1: r = relu(hagg @ w1 + b1) ----
    float r[32];
    {
        const float4* bv = (const float4*)&s[L_B1];
        #pragma unroll
        for (int j4 = 0; j4 < 8; ++j4) {
            float4 v = bv[j4];
            r[4*j4+0] = v.x; r[4*j4+1] = v.y; r[4*j4+2] = v.z; r[4*j4+3] = v.w;
        }
        const float4* wv = (const float4*)&s[L_W1];
        #pragma unroll
        for (int k = 0; k < 32; ++k) {
            float hv = hagg[k];
            #pragma unroll
            for (int j4 = 0; j4 < 8; ++j4)
                fma4(hv, wv[k*8 + j4], r + 4*j4);
        }
        #pragma unroll
        for (int j = 0; j < 32; ++j) r[j] = fmaxf(r[j], 0.f);
    }

    // ---- out2: delta = r @ w2 + b2 ----
    float dl[20];
    {
        const float4* bv = (const float4*)&s[L_B2];
        #pragma unroll
        for (int d4 = 0; d4 < 5; ++d4) {
            float4 v = bv[d4];
            dl[4*d4+0] = v.x; dl[4*d4+1] = v.y; dl[4*d4+2] = v.z; dl[4*d4+3] = v.w;
        }
        const float4* wv = (const float4*)&s[L_W2];
        #pragma unroll
        for (int k = 0; k < 32; ++k) {
            float rv = r[k];
            #pragma unroll
            for (int d4 = 0; d4 < 5; ++d4)
                fma4(rv, wv[k*5 + d4], dl + 4*d4);
        }
    }
    if (act) {
        float4* op = (float4*)(out + b*100ll + n*20);
        #pragma unroll
        for (int t = 0; t < 5; ++t)
            op[t] = make_float4(dl[4*t], dl[4*t+1], dl[4*t+2], dl[4*t+3]);
    }

    // ---- cls partial: p[c] = sum_j hagg[j] * cls_w[n*32+j][c]; reduce over 5 lanes via LDS ----
    float4 p = make_float4(0.f, 0.f, 0.f, 0.f);
    {
        const float4* cv = (const float4*)&s[L_CLS];
        #pragma unroll
        for (int j = 0; j < 32; ++j) {
            float hv = hagg[j];
            float4 w = cv[n*32 + j];
            p.x = fmaf(hv, w.x, p.x); p.y = fmaf(hv, w.y, p.y);
            p.z = fmaf(hv, w.z, p.z); p.w = fmaf(hv, w.w, p.w);
        }
    }
    if (act) {
        *(float4*)&s[L_AUX + ((wave*12 + g)*5 + n)*4] = p;
        // A output: copy precomputed softmaxed adjacency row
        #pragma unroll
        for (int q = 0; q < 5; ++q)
            out[A_OFF + b*25ll + n*5 + q] = s[L_A4 + emo*25 + n*5 + q];
    }
    asm volatile("s_waitcnt lgkmcnt(0)" ::: "memory");
    if (act && n == 0) {
        float4 acc = *(const float4*)&s[L_CLSB];
        #pragma unroll
        for (int nn = 0; nn < 5; ++nn) {
            float4 pv = *(const float4*)&s[L_AUX + ((wave*12 + g)*5 + nn)*4];
            acc.x += pv.x; acc.y += pv.y; acc.z += pv.z; acc.w += pv.w;
        }
        *(float4*)(out + LOG_OFF + b*4ll) = acc;
    }
}

extern "C" void kernel_launch(void* const* d_in, const int* in_sizes, int n_in,
                              void* d_out, int out_size, void* d_ws, size_t ws_size,
                              hipStream_t stream) {
    const float* nf      = (const float*)d_in[0];
    const int*   emo_idx = (const int*)  d_in[1];
    const float* emo_emb = (const float*)d_in[2];
    const float* A_w1    = (const float*)d_in[3];
    const float* A_b1    = (const float*)d_in[4];
    const float* A_w2    = (const float*)d_in[5];
    const float* A_b2    = (const float*)d_in[6];
    const float* enc_w   = (const float*)d_in[7];
    const float* enc_b   = (const float*)d_in[8];
    const float* ln_g    = (const float*)d_in[9];
    const float* ln_b    = (const float*)d_in[10];
    const float* out_w1  = (const float*)d_in[11];
    const float* out_b1  = (const float*)d_in[12];
    const float* out_w2  = (const float*)d_in[13];
    const float* out_b2  = (const float*)d_in[14];
    const float* cls_w   = (const float*)d_in[15];
    const float* cls_b   = (const float*)d_in[16];
    float* wsf = (float*)d_ws;
    float* outf = (float*)d_out;

    precomp_kernel<<<1, 128, 0, stream>>>(emo_emb, A_w1, A_b1, A_w2, A_b2,
                                          enc_w, enc_b, wsf);
    const int grid = (262144 + 47) / 48;   // 48 batches per block
    main_kernel<<<grid, 256, 0, stream>>>(nf, emo_idx, enc_w, ln_g, ln_b,
                                          out_w1, out_b1, out_w2, out_b2,
                                          cls_w, cls_b, wsf, outf);
}

// Round 6
// 358.761 us; speedup vs baseline: 1.0433x; 1.0433x over previous
//
#include <hip/hip_runtime.h>
#include <math.h>

#define B_TOT   262144ll
#define LOG_OFF 26214400ll   // delta = B*5*20
#define A_OFF   27262976ll   // + B*4

// workspace float offsets
#define WS_A4   0     // 4*25 softmaxed adjacencies
#define WS_ENCB 112   // 4*32 encoder bias per emotion (enc_b + e@enc_w[20:])

// LDS float offsets (only lane-dependent data lives in LDS now)
#define L_A4   0      // 100 (pad 104)
#define L_ENCB 104    // 128 -> 232
#define L_CLS  232    // 640 -> 872
#define L_HST  872    // 4 waves * 60 rows * pitch 36 = 8640 -> 9512
#define L_AUX  9512   // 48 batches * 5 * 4 = 960 -> 10472
#define L_TOT  10472  // 41.9 KB -> 3 blocks/CU

__device__ __forceinline__ void fma4(float a, const float4& w, float* acc) {
    acc[0] = fmaf(a, w.x, acc[0]);
    acc[1] = fmaf(a, w.y, acc[1]);
    acc[2] = fmaf(a, w.z, acc[2]);
    acc[3] = fmaf(a, w.w, acc[3]);
}

// ---------- precompute: 4 adjacency matrices + 4 encoder bias vectors ----------
__global__ void __launch_bounds__(128) precomp_kernel(
    const float* __restrict__ emo_emb, const float* __restrict__ A_w1,
    const float* __restrict__ A_b1, const float* __restrict__ A_w2,
    const float* __restrict__ A_b2, const float* __restrict__ enc_w,
    const float* __restrict__ enc_b, float* __restrict__ wsf)
{
    __shared__ float hid[4][32];
    __shared__ float av[4][25];
    const int t = threadIdx.x;
    const int c = t >> 5, m = t & 31;

    float acc = A_b1[m];
    #pragma unroll
    for (int k = 0; k < 16; ++k)
        acc = fmaf(emo_emb[c*16 + k], A_w1[k*32 + m], acc);
    hid[c][m] = fmaxf(acc, 0.f);
    __syncthreads();

    if (m < 25) {
        float a2 = A_b2[m];
        #pragma unroll
        for (int k = 0; k < 32; ++k)
            a2 = fmaf(hid[c][k], A_w2[k*25 + m], a2);
        av[c][m] = a2;
    }
    __syncthreads();

    if (m < 5) {
        float v[5];
        #pragma unroll
        for (int q = 0; q < 5; ++q) v[q] = av[c][m*5 + q];
        float mx = v[0];
        #pragma unroll
        for (int q = 1; q < 5; ++q) mx = fmaxf(mx, v[q]);
        float ssum = 0.f;
        #pragma unroll
        for (int q = 0; q < 5; ++q) { v[q] = expf(v[q] - mx); ssum += v[q]; }
        float inv = 1.f / ssum;
        #pragma unroll
        for (int q = 0; q < 5; ++q) wsf[WS_A4 + c*25 + m*5 + q] = v[q] * inv;
    }

    float eb = enc_b[m];
    #pragma unroll
    for (int k = 0; k < 16; ++k)
        eb = fmaf(emo_emb[c*16 + k], enc_w[(20 + k)*32 + m], eb);
    wsf[WS_ENCB + c*32 + m] = eb;
}

// ---------- main: lane = (batch, node); weights via uniform scalar (SGPR) loads ----------
__global__ void __launch_bounds__(256) main_kernel(
    const float* __restrict__ nf, const int* __restrict__ emo_idx,
    const float* __restrict__ enc_w, const float* __restrict__ ln_g,
    const float* __restrict__ ln_b, const float* __restrict__ w1,
    const float* __restrict__ b1, const float* __restrict__ w2,
    const float* __restrict__ b2, const float* __restrict__ clsw,
    const float* __restrict__ clsb, const float* __restrict__ wsf,
    float* __restrict__ out)
{
    __shared__ __align__(16) float s[L_TOT];
    const int tid = threadIdx.x;

    // stage ONLY lane-index-dependent tables in LDS
    for (int t = tid; t < 640; t += 256) s[L_CLS + t] = clsw[t];
    if (tid < 128) s[L_ENCB + tid] = wsf[WS_ENCB + tid];
    if (tid < 100) s[L_A4 + tid]   = wsf[WS_A4 + tid];
    __syncthreads();

    const int wave = tid >> 6, lane = tid & 63;
    const int g = lane / 5, n = lane - g*5;            // batch-in-wave, node
    const long long b = (long long)blockIdx.x * 48 + wave*12 + g;
    const bool act = (lane < 60) && (b < B_TOT);

    // uniform (SGPR) views of weights in global memory
    const float4* encw4 = (const float4*)enc_w;   // rows 0..19 used
    const float4* w1_4  = (const float4*)w1;
    const float4* w2_4  = (const float4*)w2;
    const float4* b1_4  = (const float4*)b1;
    const float4* lg4   = (const float4*)ln_g;
    const float4* lb4   = (const float4*)ln_b;
    const float4* b2_4  = (const float4*)b2;

    int emo = 0;
    float x[20];
    #pragma unroll
    for (int d = 0; d < 20; ++d) x[d] = 0.f;
    if (act) {
        emo = emo_idx[b];
        const float4* xp = (const float4*)(nf + b*100ll + n*20);
        #pragma unroll
        for (int t = 0; t < 5; ++t) {
            float4 v = xp[t];
            x[4*t+0] = v.x; x[4*t+1] = v.y; x[4*t+2] = v.z; x[4*t+3] = v.w;
        }
    }

    // ---- encoder: y = x @ enc_w[:20] + encb[emo] (encb per-lane from LDS) ----
    float y[32];
    {
        const float4* ev = (const float4*)&s[L_ENCB];
        #pragma unroll
        for (int j4 = 0; j4 < 8; ++j4) {
            float4 v = ev[emo*8 + j4];
            y[4*j4+0] = v.x; y[4*j4+1] = v.y; y[4*j4+2] = v.z; y[4*j4+3] = v.w;
        }
        #pragma unroll
        for (int d = 0; d < 20; ++d) {
            float xv = x[d];
            #pragma unroll
            for (int j4 = 0; j4 < 8; ++j4)
                fma4(xv, encw4[d*8 + j4], y + 4*j4);
        }
    }

    // ---- LayerNorm + relu (in-lane over 32 regs; g/b from SGPR) ----
    {
        float sum = 0.f;
        #pragma unroll
        for (int j = 0; j < 32; ++j) sum += y[j];
        float mu = sum * 0.03125f;
        float sq = 0.f;
        #pragma unroll
        for (int j = 0; j < 32; ++j) { float d = y[j] - mu; sq = fmaf(d, d, sq); }
        float rs = rsqrtf(fmaf(sq, 0.03125f, 1e-5f));
        #pragma unroll
        for (int j4 = 0; j4 < 8; ++j4) {
            float4 gg = lg4[j4], bb = lb4[j4];
            float h0 = fmaf((y[4*j4+0] - mu) * rs, gg.x, bb.x);
            float h1 = fmaf((y[4*j4+1] - mu) * rs, gg.y, bb.y);
            float h2 = fmaf((y[4*j4+2] - mu) * rs, gg.z, bb.z);
            float h3 = fmaf((y[4*j4+3] - mu) * rs, gg.w, bb.w);
            y[4*j4+0] = fmaxf(h0, 0.f); y[4*j4+1] = fmaxf(h1, 0.f);
            y[4*j4+2] = fmaxf(h2, 0.f); y[4*j4+3] = fmaxf(h3, 0.f);
        }
    }

    // ---- stage h in LDS (per-wave region; cross-lane dep within wave only) ----
    if (act) {
        float4* hp = (float4*)&s[L_HST + (wave*60 + lane)*36];
        #pragma unroll
        for (int t = 0; t < 8; ++t)
            hp[t] = make_float4(y[4*t], y[4*t+1], y[4*t+2], y[4*t+3]);
    }
    asm volatile("s_waitcnt lgkmcnt(0)" ::: "memory");

    // ---- agg: h_agg[n] = sum_nn A4[emo][n][nn] * h[g,nn] ----
    float hagg[32];
    #pragma unroll
    for (int j = 0; j < 32; ++j) hagg[j] = 0.f;
    if (act) {
        #pragma unroll
        for (int nn = 0; nn < 5; ++nn) {
            float a = s[L_A4 + emo*25 + n*5 + nn];
            const float4* rp = (const float4*)&s[L_HST + (wave*60 + g*5 + nn)*36];
            #pragma unroll
            for (int t = 0; t < 8; ++t)
                fma4(a, rp[t], hagg + 4*t);
        }
    }

    // ---- out1: r = relu(hagg @ w1 + b1), w1/b1 from SGPR ----
    float r[32];
    {
        #pragma unroll
        for (int j4 = 0; j4 < 8; ++j4) {
            float4 v = b1_4[j4];
            r[4*j4+0] = v.x; r[4*j4+1] = v.y; r[4*j4+2] = v.z; r[4*j4+3] = v.w;
        }
        #pragma unroll
        for (int k = 0; k < 32; ++k) {
            float hv = hagg[k];
            #pragma unroll
            for (int j4 = 0; j4 < 8; ++j4)
                fma4(hv, w1_4[k*8 + j4], r + 4*j4);
        }
        #pragma unroll
        for (int j = 0; j < 32; ++j) r[j] = fmaxf(r[j], 0.f);
    }

    // ---- out2: delta = r @ w2 + b2, w2/b2 from SGPR ----
    float dl[20];
    {
        #pragma unroll
        for (int d4 = 0; d4 < 5; ++d4) {
            float4 v = b2_4[d4];
            dl[4*d4+0] = v.x; dl[4*d4+1] = v.y; dl[4*d4+2] = v.z; dl[4*d4+3] = v.w;
        }
        #pragma unroll
        for (int k = 0; k < 32; ++k) {
            float rv = r[k];
            #pragma unroll
            for (int d4 = 0; d4 < 5; ++d4)
                fma4(rv, w2_4[k*5 + d4], dl + 4*d4);
        }
    }
    if (act) {
        float4* op = (float4*)(out + b*100ll + n*20);
        #pragma unroll
        for (int t = 0; t < 5; ++t)
            op[t] = make_float4(dl[4*t], dl[4*t+1], dl[4*t+2], dl[4*t+3]);
    }

    // ---- cls partial: p[c] = sum_j hagg[j] * cls_w[n*32+j][c] (n-dep -> LDS) ----
    float4 p = make_float4(0.f, 0.f, 0.f, 0.f);
    {
        const float4* cv = (const float4*)&s[L_CLS];
        #pragma unroll
        for (int j = 0; j < 32; ++j) {
            float hv = hagg[j];
            float4 w = cv[n*32 + j];
            p.x = fmaf(hv, w.x, p.x); p.y = fmaf(hv, w.y, p.y);
            p.z = fmaf(hv, w.z, p.z); p.w = fmaf(hv, w.w, p.w);
        }
    }
    // cls bias via uniform load (hoisted, outside divergent branch)
    float4 cb = *(const float4*)clsb;
    if (act) {
        *(float4*)&s[L_AUX + ((wave*12 + g)*5 + n)*4] = p;
        #pragma unroll
        for (int q = 0; q < 5; ++q)
            out[A_OFF + b*25ll + n*5 + q] = s[L_A4 + emo*25 + n*5 + q];
    }
    asm volatile("s_waitcnt lgkmcnt(0)" ::: "memory");
    if (act && n == 0) {
        float4 acc = cb;
        #pragma unroll
        for (int nn = 0; nn < 5; ++nn) {
            float4 pv = *(const float4*)&s[L_AUX + ((wave*12 + g)*5 + nn)*4];
            acc.x += pv.x; acc.y += pv.y; acc.z += pv.z; acc.w += pv.w;
        }
        *(float4*)(out + LOG_OFF + b*4ll) = acc;
    }
}

extern "C" void kernel_launch(void* const* d_in, const int* in_sizes, int n_in,
                              void* d_out, int out_size, void* d_ws, size_t ws_size,
                              hipStream_t stream) {
    const float* nf      = (const float*)d_in[0];
    const int*   emo_idx = (const int*)  d_in[1];
    const float* emo_emb = (const float*)d_in[2];
    const float* A_w1    = (const float*)d_in[3];
    const float* A_b1    = (const float*)d_in[4];
    const float* A_w2    = (const float*)d_in[5];
    const float* A_b2    = (const float*)d_in[6];
    const float* enc_w   = (const float*)d_in[7];
    const float* enc_b   = (const float*)d_in[8];
    const float* ln_g    = (const float*)d_in[9];
    const float* ln_b    = (const float*)d_in[10];
    const float* out_w1  = (const float*)d_in[11];
    const float* out_b1  = (const float*)d_in[12];
    const float* out_w2  = (const float*)d_in[13];
    const float* out_b2  = (const float*)d_in[14];
    const float* cls_w   = (const float*)d_in[15];
    const float* cls_b   = (const float*)d_in[16];
    float* wsf = (float*)d_ws;
    float* outf = (float*)d_out;

    precomp_kernel<<<1, 128, 0, stream>>>(emo_emb, A_w1, A_b1, A_w2, A_b2,
                                          enc_w, enc_b, wsf);
    const int grid = (262144 + 47) / 48;   // 48 batches per block
    main_kernel<<<grid, 256, 0, stream>>>(nf, emo_idx, enc_w, ln_g, ln_b,
                                          out_w1, out_b1, out_w2, out_b2,
                                          cls_w, cls_b, wsf, outf);
}

// Round 8
// 336.706 us; speedup vs baseline: 1.1116x; 1.0655x over previous
//
#include <hip/hip_runtime.h>
#include <math.h>

#define B_TOT   262144ll
#define LOG_OFF 26214400ll   // delta = B*5*20
#define A_OFF   27262976ll   // + B*4

// workspace float offsets
#define WS_A4   0     // 4*25 softmaxed adjacencies
#define WS_ENCB 112   // 4*32 encoder bias per emotion (enc_b + e@enc_w[20:])

// LDS float offsets (lane-dependent data only; padded/swizzled per R6 counters)
#define L_A4   0      // 100 used (pad 104)
#define L_ENCB 104    // 4 emo * 36 (pad 9 float4) = 144 -> 248
#define L_CLS  248    // 5 n-blocks * 132 (pad 33 float4) = 660 -> 908, pad 912
#define L_HST  912    // 4 waves * 60 rows * 32 floats (XOR-swizzled) = 7680 -> 8592
#define L_AUX  8592   // 240 rows * 4 = 960 -> 9552
#define L_TOT  9552   // 38208 B -> 4 blocks/CU (16 waves cap)

__device__ __forceinline__ void fma4(float a, const float4& w, float* acc) {
    acc[0] = fmaf(a, w.x, acc[0]);
    acc[1] = fmaf(a, w.y, acc[1]);
    acc[2] = fmaf(a, w.z, acc[2]);
    acc[3] = fmaf(a, w.w, acc[3]);
}

// ---------- precompute: 4 adjacency matrices + 4 encoder bias vectors ----------
__global__ void __launch_bounds__(128) precomp_kernel(
    const float* __restrict__ emo_emb, const float* __restrict__ A_w1,
    const float* __restrict__ A_b1, const float* __restrict__ A_w2,
    const float* __restrict__ A_b2, const float* __restrict__ enc_w,
    const float* __restrict__ enc_b, float* __restrict__ wsf)
{
    __shared__ float hid[4][32];
    __shared__ float av[4][25];
    const int t = threadIdx.x;
    const int c = t >> 5, m = t & 31;

    float acc = A_b1[m];
    #pragma unroll
    for (int k = 0; k < 16; ++k)
        acc = fmaf(emo_emb[c*16 + k], A_w1[k*32 + m], acc);
    hid[c][m] = fmaxf(acc, 0.f);
    __syncthreads();

    if (m < 25) {
        float a2 = A_b2[m];
        #pragma unroll
        for (int k = 0; k < 32; ++k)
            a2 = fmaf(hid[c][k], A_w2[k*25 + m], a2);
        av[c][m] = a2;
    }
    __syncthreads();

    if (m < 5) {
        float v[5];
        #pragma unroll
        for (int q = 0; q < 5; ++q) v[q] = av[c][m*5 + q];
        float mx = v[0];
        #pragma unroll
        for (int q = 1; q < 5; ++q) mx = fmaxf(mx, v[q]);
        float ssum = 0.f;
        #pragma unroll
        for (int q = 0; q < 5; ++q) { v[q] = expf(v[q] - mx); ssum += v[q]; }
        float inv = 1.f / ssum;
        #pragma unroll
        for (int q = 0; q < 5; ++q) wsf[WS_A4 + c*25 + m*5 + q] = v[q] * inv;
    }

    float eb = enc_b[m];
    #pragma unroll
    for (int k = 0; k < 16; ++k)
        eb = fmaf(emo_emb[c*16 + k], enc_w[(20 + k)*32 + m], eb);
    wsf[WS_ENCB + c*32 + m] = eb;
}

// ---------- main: lane = (batch, node); weights via uniform scalar loads ----------
__global__ void __launch_bounds__(256) main_kernel(
    const float* __restrict__ nf, const int* __restrict__ emo_idx,
    const float* __restrict__ enc_w, const float* __restrict__ ln_g,
    const float* __restrict__ ln_b, const float* __restrict__ w1,
    const float* __restrict__ b1, const float* __restrict__ w2,
    const float* __restrict__ b2, const float* __restrict__ clsw,
    const float* __restrict__ clsb, const float* __restrict__ wsf,
    float* __restrict__ out)
{
    __shared__ __align__(16) float s[L_TOT];
    const int tid = threadIdx.x;
    const int wave = tid >> 6, lane = tid & 63;
    const int g = lane / 5, n = lane - g*5;            // batch-in-wave, node
    const long long b = (long long)blockIdx.x * 48 + wave*12 + g;
    const bool act = (lane < 60) && (b < B_TOT);

    // ---- issue per-lane global loads FIRST (latency hides under staging+barrier) ----
    int emo = 0;
    float x[20];
    #pragma unroll
    for (int d = 0; d < 20; ++d) x[d] = 0.f;
    if (act) {
        emo = emo_idx[b];
        const float4* xp = (const float4*)(nf + b*100ll + n*20);
        #pragma unroll
        for (int t = 0; t < 5; ++t) {
            float4 v = xp[t];
            x[4*t+0] = v.x; x[4*t+1] = v.y; x[4*t+2] = v.z; x[4*t+3] = v.w;
        }
    }

    // ---- stage lane-index-dependent tables in LDS (padded layouts) ----
    for (int t = tid; t < 640; t += 256) {
        int nblk = t >> 7, within = t & 127;           // cls row-block n, offset
        s[L_CLS + nblk*132 + within] = clsw[t];
    }
    if (tid < 128) s[L_ENCB + (tid >> 5)*36 + (tid & 31)] = wsf[WS_ENCB + tid];
    if (tid < 100) s[L_A4 + tid] = wsf[WS_A4 + tid];
    __syncthreads();

    // uniform (SGPR) views of weights in global memory
    const float4* encw4 = (const float4*)enc_w;   // rows 0..19 used
    const float4* w1_4  = (const float4*)w1;
    const float4* w2_4  = (const float4*)w2;
    const float4* b1_4  = (const float4*)b1;
    const float4* lg4   = (const float4*)ln_g;
    const float4* lb4   = (const float4*)ln_b;
    const float4* b2_4  = (const float4*)b2;
    float4 cb = *(const float4*)clsb;

    // ---- encoder: y = x @ enc_w[:20] + encb[emo] ----
    float y[32];
    {
        const float4* ev = (const float4*)&s[L_ENCB];
        #pragma unroll
        for (int j4 = 0; j4 < 8; ++j4) {
            float4 v = ev[emo*9 + j4];                 // padded stride 9
            y[4*j4+0] = v.x; y[4*j4+1] = v.y; y[4*j4+2] = v.z; y[4*j4+3] = v.w;
        }
        #pragma unroll
        for (int d = 0; d < 20; ++d) {
            float xv = x[d];
            #pragma unroll
            for (int j4 = 0; j4 < 8; ++j4)
                fma4(xv, encw4[d*8 + j4], y + 4*j4);
        }
    }

    // ---- LayerNorm + relu (in-lane over 32 regs) ----
    {
        float sum = 0.f;
        #pragma unroll
        for (int j = 0; j < 32; ++j) sum += y[j];
        float mu = sum * 0.03125f;
        float sq = 0.f;
        #pragma unroll
        for (int j = 0; j < 32; ++j) { float d = y[j] - mu; sq = fmaf(d, d, sq); }
        float rs = rsqrtf(fmaf(sq, 0.03125f, 1e-5f));
        #pragma unroll
        for (int j4 = 0; j4 < 8; ++j4) {
            float4 gg = lg4[j4], bb = lb4[j4];
            float h0 = fmaf((y[4*j4+0] - mu) * rs, gg.x, bb.x);
            float h1 = fmaf((y[4*j4+1] - mu) * rs, gg.y, bb.y);
            float h2 = fmaf((y[4*j4+2] - mu) * rs, gg.z, bb.z);
            float h3 = fmaf((y[4*j4+3] - mu) * rs, gg.w, bb.w);
            y[4*j4+0] = fmaxf(h0, 0.f); y[4*j4+1] = fmaxf(h1, 0.f);
            y[4*j4+2] = fmaxf(h2, 0.f); y[4*j4+3] = fmaxf(h3, 0.f);
        }
    }

    // ---- stage h in LDS: pitch 32, XOR-swizzled slot = t ^ (row&7) ----
    // MUST be act-guarded: lanes 60..63 of wave w would alias wave w+1's rows
    // (w*60+60 == (w+1)*60+0) — caused R7's race/corruption.
    if (act) {
        const int row = wave*60 + lane;
        const int sw = row & 7;
        float4* hp = (float4*)&s[L_HST + row*32];
        #pragma unroll
        for (int t = 0; t < 8; ++t)
            hp[t ^ sw] = make_float4(y[4*t], y[4*t+1], y[4*t+2], y[4*t+3]);
    }
    asm volatile("s_waitcnt lgkmcnt(0)" ::: "memory");

    // ---- agg: h_agg[n] = sum_nn A4[emo][n][nn] * h[g,nn] ----
    float hagg[32];
    float av5[5];                                      // A row, reused for A-output
    #pragma unroll
    for (int j = 0; j < 32; ++j) hagg[j] = 0.f;
    #pragma unroll
    for (int q = 0; q < 5; ++q) av5[q] = 0.f;
    if (act) {
        #pragma unroll
        for (int nn = 0; nn < 5; ++nn) {
            float a = s[L_A4 + emo*25 + n*5 + nn];
            av5[nn] = a;
            const int row2 = wave*60 + g*5 + nn;
            const int sw2 = row2 & 7;
            const float4* rp = (const float4*)&s[L_HST + row2*32];
            #pragma unroll
            for (int t = 0; t < 8; ++t)
                fma4(a, rp[t ^ sw2], hagg + 4*t);
        }
    }

    // ---- out1: r = relu(hagg @ w1 + b1) ----
    float r[32];
    {
        #pragma unroll
        for (int j4 = 0; j4 < 8; ++j4) {
            float4 v = b1_4[j4];
            r[4*j4+0] = v.x; r[4*j4+1] = v.y; r[4*j4+2] = v.z; r[4*j4+3] = v.w;
        }
        #pragma unroll
        for (int k = 0; k < 32; ++k) {
            float hv = hagg[k];
            #pragma unroll
            for (int j4 = 0; j4 < 8; ++j4)
                fma4(hv, w1_4[k*8 + j4], r + 4*j4);
        }
        #pragma unroll
        for (int j = 0; j < 32; ++j) r[j] = fmaxf(r[j], 0.f);
    }

    // ---- out2: delta = r @ w2 + b2 ----
    float dl[20];
    {
        #pragma unroll
        for (int d4 = 0; d4 < 5; ++d4) {
            float4 v = b2_4[d4];
            dl[4*d4+0] = v.x; dl[4*d4+1] = v.y; dl[4*d4+2] = v.z; dl[4*d4+3] = v.w;
        }
        #pragma unroll
        for (int k = 0; k < 32; ++k) {
            float rv = r[k];
            #pragma unroll
            for (int d4 = 0; d4 < 5; ++d4)
                fma4(rv, w2_4[k*5 + d4], dl + 4*d4);
        }
    }
    if (act) {
        float4* op = (float4*)(out + b*100ll + n*20);
        #pragma unroll
        for (int t = 0; t < 5; ++t)
            op[t] = make_float4(dl[4*t], dl[4*t+1], dl[4*t+2], dl[4*t+3]);
    }

    // ---- cls partial: p[c] = sum_j hagg[j] * cls_w[n*32+j][c] (padded stride 33) ----
    float4 p = make_float4(0.f, 0.f, 0.f, 0.f);
    {
        const float4* cv = (const float4*)&s[L_CLS];
        #pragma unroll
        for (int j = 0; j < 32; ++j) {
            float hv = hagg[j];
            float4 w = cv[n*33 + j];
            p.x = fmaf(hv, w.x, p.x); p.y = fmaf(hv, w.y, p.y);
            p.z = fmaf(hv, w.z, p.z); p.w = fmaf(hv, w.w, p.w);
        }
    }
    if (act) {
        *(float4*)&s[L_AUX + (wave*60 + lane)*4] = p;
        // A output from the registers captured during agg
        #pragma unroll
        for (int q = 0; q < 5; ++q)
            out[A_OFF + b*25ll + n*5 + q] = av5[q];
    }
    asm volatile("s_waitcnt lgkmcnt(0)" ::: "memory");
    if (act && n == 0) {
        float4 acc = cb;
        #pragma unroll
        for (int nn = 0; nn < 5; ++nn) {
            float4 pv = *(const float4*)&s[L_AUX + (wave*60 + g*5 + nn)*4];
            acc.x += pv.x; acc.y += pv.y; acc.z += pv.z; acc.w += pv.w;
        }
        *(float4*)(out + LOG_OFF + b*4ll) = acc;
    }
}

extern "C" void kernel_launch(void* const* d_in, const int* in_sizes, int n_in,
                              void* d_out, int out_size, void* d_ws, size_t ws_size,
                              hipStream_t stream) {
    const float* nf      = (const float*)d_in[0];
    const int*   emo_idx = (const int*)  d_in[1];
    const float* emo_emb = (const float*)d_in[2];
    const float* A_w1    = (const float*)d_in[3];
    const float* A_b1    = (const float*)d_in[4];
    const float* A_w2    = (const float*)d_in[5];
    const float* A_b2    = (const float*)d_in[6];
    const float* enc_w   = (const float*)d_in[7];
    const float* enc_b   = (const float*)d_in[8];
    const float* ln_g    = (const float*)d_in[9];
    const float* ln_b    = (const float*)d_in[10];
    const float* out_w1  = (const float*)d_in[11];
    const float* out_b1  = (const float*)d_in[12];
    const float* out_w2  = (const float*)d_in[13];
    const float* out_b2  = (const float*)d_in[14];
    const float* cls_w   = (const float*)d_in[15];
    const float* cls_b   = (const float*)d_in[16];
    float* wsf = (float*)d_ws;
    float* outf = (float*)d_out;

    precomp_kernel<<<1, 128, 0, stream>>>(emo_emb, A_w1, A_b1, A_w2, A_b2,
                                          enc_w, enc_b, wsf);
    const int grid = (262144 + 47) / 48;   // 48 batches per block
    main_kernel<<<grid, 256, 0, stream>>>(nf, emo_idx, enc_w, ln_g, ln_b,
                                          out_w1, out_b1, out_w2, out_b2,
                                          cls_w, cls_b, wsf, outf);
}